// Round 3
// baseline (339.798 us; speedup 1.0000x reference)
//
#include <hip/hip_runtime.h>
#include <cstddef>

// EGNN layer. Round 12: re-run of R11 (container infra failure, no data).
// LDS diet -> 3 blocks/CU (24 waves/CU).
//  - u_s activation tile: XOR bank-swizzle instead of +8 pad (18.4KB -> 16KB)
//  - w1c frags stored compact (K=16 real rows only, lanes 0..31): 4KB -> 2KB
//  - LDS 56.8KB -> 52.5KB: 2 -> 3 blocks/CU; grid 768, __launch_bounds__(512,6)
//  - everything else (prep structure, node, aggregation atomics) unchanged
//
// MFMA fragment layouts (gfx950, 16x16x32 bf16, verified learn_hip m89/m91):
//   A: lane holds A[m=lane&15][k=(lane>>4)*8 + j], j=0..7
//   B: lane holds B[k=(lane>>4)*8 + j][n=lane&15]
//   C/D: lane reg r holds D[row=(lane>>4)*4+r][col=lane&15]

#define N_NODES 50000
#define M_EDGES 800000

typedef __attribute__((ext_vector_type(8))) short bf16x8;
typedef __attribute__((ext_vector_type(4))) short bf16x4;
typedef __attribute__((ext_vector_type(2))) short bf16x2;
typedef __attribute__((ext_vector_type(4))) float f32x4;

// ---- global wfrag layout (short offsets). Edge section (first WEDGE_SHORTS)
// is copied verbatim into edge-kernel LDS, so LDS offsets == these offsets.
#define WOFF_WA    0        // w1e rows 1..64   [t*2+s], 8 frags x 512
#define WOFF_WB    4096     // w1e rows 65..128 [t*2+s], 8 frags x 512
#define WOFF_W1C   8192     // w1e rows 129..144 COMPACT: 4 frags x 256 (lanes 0..31)
#define WOFF_W2    9216     // w2e [t*2+s], 8 frags x 512
#define WOFF_WC1   13312    // wc1 [t*2+s], 8 frags x 512
#define WEDGE_SHORTS 17408  // 34816 B staged into edge LDS
#define WOFF_WN1   17408    // wn1 (K=128) [t*4+s], 16 frags x 512
#define WOFF_WN2   25600    // wn2 [t*2+s], 8 frags x 512
#define WTOT_SHORTS 29696

__device__ __forceinline__ float silu_f(float v) {
    return v / (1.0f + __expf(-v));
}

__device__ __forceinline__ short f2bf(float f) {   // RNE float->bf16
    union { float f; unsigned u; } v; v.f = f;
    unsigned r = v.u + 0x7fffu + ((v.u >> 16) & 1u);
    return (short)(r >> 16);
}

__device__ __forceinline__ void atomic_pk_add_bf16(unsigned short* p, unsigned int packed) {
#if __has_builtin(__builtin_amdgcn_global_atomic_fadd_v2bf16)
    typedef bf16x2 __attribute__((address_space(1))) gbf16x2;
    union { unsigned int u; bf16x2 v; } c; c.u = packed;
    __builtin_amdgcn_global_atomic_fadd_v2bf16((gbf16x2*)(unsigned long long)p, c.v);
#else
    asm volatile("global_atomic_pk_add_bf16 %0, %1, off"
                 :: "v"((unsigned long long)p), "v"(packed) : "memory");
#endif
}

#define LDS_FENCE() __asm__ volatile("" ::: "memory")

// u_s swizzle: logical (edge e, short s in [0,64)) -> physical short index.
// XOR of short-index bits 3..5 with e&7 spreads the 128B rows across banks;
// keeps 16B alignment for the bf16x8 reads (s multiple of 8) and 8B for
// the bf16x4 writes (s multiple of 4). Bit 0/1 untouched -> the packed
// uint reads (s multiple of 2) stay contiguous.
__device__ __forceinline__ int us_idx(int e, int s) {
    return e * 64 + (s ^ ((e & 7) << 3));
}

// ---------------------------------------------------------------- K0: prep
// wfrag conversion + h->bf16 + zero tot_msg/totf4, grid-strided.
#define PREP_W   (60 * 64)                  // 3840 (60 64-lane units)
#define PREP_H   (N_NODES * 8)              // 400000  (bf16x8 items of h)
#define PREP_ZM  (N_NODES * 8)              // 400000  (uint4 items of tot_msg)
#define PREP_ZF  (N_NODES)                  // 50000   (f32x4 items of totf4)
#define PREP_TOTAL (PREP_W + PREP_H + PREP_ZM + PREP_ZF)

__global__ __launch_bounds__(256) void prep_kernel(
    const float* __restrict__ w1e, const float* __restrict__ w2e,
    const float* __restrict__ wc1, const float* __restrict__ wn1,
    const float* __restrict__ wn2, const float* __restrict__ h,
    unsigned short* __restrict__ wfrag, unsigned short* __restrict__ h_bf,
    unsigned short* __restrict__ tot_msg, float* __restrict__ totf4)
{
    for (int gid = blockIdx.x * 256 + threadIdx.x; gid < PREP_TOTAL;
         gid += gridDim.x * 256) {
        if (gid < PREP_W) {
            const int unit = gid >> 6, lane = gid & 63;
            const int l15 = lane & 15, l4 = lane >> 4;
            if (unit >= 16 && unit < 20) {
                // w1c compact: 16 real K-rows, lanes 0..31 (k = l4*8+j, l4<2)
                if (lane < 32) {
                    const int t = unit - 16;
                    const int col = t * 16 + l15;
                    bf16x8 v;
                    #pragma unroll
                    for (int j = 0; j < 8; ++j)
                        v[j] = f2bf(w1e[(size_t)(129 + l4 * 8 + j) * 64 + col]);
                    *(bf16x8*)(wfrag + WOFF_W1C + t * 256 + lane * 8) = v;
                }
            } else {
                const float* src; int k0, t, dst;
                if (unit < 8)       { src = w1e; k0 = 1 + (unit & 1) * 32; t = unit >> 1; dst = WOFF_WA + unit * 512; }
                else if (unit < 16) { const int f = unit - 8;  src = w1e; k0 = 65 + (f & 1) * 32; t = f >> 1; dst = WOFF_WB  + f * 512; }
                else if (unit < 28) { const int f = unit - 20; src = w2e; k0 = (f & 1) * 32;      t = f >> 1; dst = WOFF_W2  + f * 512; }
                else if (unit < 36) { const int f = unit - 28; src = wc1; k0 = (f & 1) * 32;      t = f >> 1; dst = WOFF_WC1 + f * 512; }
                else if (unit < 52) { const int f = unit - 36; src = wn1; k0 = (f & 3) * 32;      t = f >> 2; dst = WOFF_WN1 + f * 512; }
                else                { const int f = unit - 52; src = wn2; k0 = (f & 1) * 32;      t = f >> 1; dst = WOFF_WN2 + f * 512; }
                const int col = t * 16 + l15;
                bf16x8 v;
                #pragma unroll
                for (int j = 0; j < 8; ++j)
                    v[j] = f2bf(src[(size_t)(k0 + l4 * 8 + j) * 64 + col]);
                *(bf16x8*)(wfrag + dst + lane * 8) = v;
            }
        } else if (gid < PREP_W + PREP_H) {
            const int j = gid - PREP_W;
            const float* src = h + (size_t)j * 8;
            const f32x4 f0 = *(const f32x4*)src;
            const f32x4 f1 = *(const f32x4*)(src + 4);
            bf16x8 v;
            #pragma unroll
            for (int k = 0; k < 4; ++k) { v[k] = f2bf(f0[k]); v[4 + k] = f2bf(f1[k]); }
            *(bf16x8*)(h_bf + (size_t)j * 8) = v;
        } else if (gid < PREP_W + PREP_H + PREP_ZM) {
            const int j = gid - PREP_W - PREP_H;
            ((uint4*)tot_msg)[j] = make_uint4(0u, 0u, 0u, 0u);
        } else {
            const int j = gid - PREP_W - PREP_H - PREP_ZM;
            const f32x4 zf = {0.f, 0.f, 0.f, 0.f};
            ((f32x4*)totf4)[j] = zf;
        }
    }
}

// ---------------------------------------------------------------- K2: edges
// 512 threads = 8 waves; each wave handles 16 edges per group-iter
// (128 edges per block per iter). All weight frags in LDS (34.8KB).
// LDS total 52.5KB -> 3 blocks/CU (24 waves/CU).
__global__ __launch_bounds__(512, 6) void edge_kernel(
    const float* __restrict__ x, const float* __restrict__ edge_fea,
    const float* __restrict__ w1e, const float* __restrict__ b1e,
    const float* __restrict__ b2e, const float* __restrict__ bc1,
    const float* __restrict__ wc2, const float* __restrict__ bc2,
    const int* __restrict__ row, const int* __restrict__ col,
    const unsigned short* __restrict__ h_bf,
    const unsigned short* __restrict__ wfrag,
    unsigned short* __restrict__ tot_msg, float* __restrict__ totf4)
{
    __shared__ __align__(16) short wlds[WEDGE_SHORTS];  // 34816 B
    __shared__ __align__(16) short u_s[8][1024];        // 16384 B (swizzled)
    __shared__ f32x4 cst_s[5][16];                      // 1280 B

    const int tid  = threadIdx.x;
    const int lane = tid & 63;
    const int wv   = __builtin_amdgcn_readfirstlane(tid >> 6);
    const int l15  = lane & 15;
    const int l4   = lane >> 4;

    {   // stage ALL edge-side weight frags into LDS: 34816 B = 2176 uint4
        const uint4* src = (const uint4*)wfrag;
        uint4* dst = (uint4*)wlds;
        for (int i = tid; i < 2176; i += 512) dst[i] = src[i];
    }
    if (tid < 16)       cst_s[0][tid]      = *(const f32x4*)(b1e + tid * 4);
    else if (tid < 32)  cst_s[1][tid - 16] = *(const f32x4*)(w1e + (tid - 16) * 4);
    else if (tid < 48)  cst_s[2][tid - 32] = *(const f32x4*)(b2e + (tid - 32) * 4);
    else if (tid < 64)  cst_s[3][tid - 48] = *(const f32x4*)(bc1 + (tid - 48) * 4);
    else if (tid < 80)  cst_s[4][tid - 64] = *(const f32x4*)(wc2 + (tid - 64) * 4);

    const float bc2v = bc2[0];
    __syncthreads();

    short* const us = &u_s[wv][0];
    const f32x4 zf = {0.f, 0.f, 0.f, 0.f};
    const bf16x8 zv8 = {0, 0, 0, 0, 0, 0, 0, 0};

    // ---- pipelined group loop (128 edges per group)
    const int groups = M_EDGES / 128;    // 6250
    const int gstep  = gridDim.x;        // 768 (persistent blocks, 3/CU)
    int g = blockIdx.x;

    int   cr;
    float xr0, xr1, xr2, xc0, xc1, xc2;
    bf16x8 bhr0, bhr1, bhc0, bhc1;       // h[row], h[col] B-frags (K=64)
    f32x4 cf0 = zf, cf1 = zf;            // fea halves (l4<2 only)

    auto issue_gathers = [&](int gg, int rI, int cI) {
        const float* xr = x + (size_t)rI * 3;
        const float* xc = x + (size_t)cI * 3;
        xr0 = xr[0]; xr1 = xr[1]; xr2 = xr[2];
        xc0 = xc[0]; xc1 = xc[1]; xc2 = xc[2];
        const unsigned short* hr = h_bf + (size_t)rI * 64;
        const unsigned short* hc = h_bf + (size_t)cI * 64;
        bhr0 = *(const bf16x8*)(hr + l4 * 8);
        bhr1 = *(const bf16x8*)(hr + 32 + l4 * 8);
        bhc0 = *(const bf16x8*)(hc + l4 * 8);
        bhc1 = *(const bf16x8*)(hc + 32 + l4 * 8);
        if (l4 < 2) {
            const float* fp = edge_fea + (size_t)(gg * 128 + wv * 16 + l15) * 16 + l4 * 8;
            cf0 = *(const f32x4*)fp;
            cf1 = *(const f32x4*)(fp + 4);
        }
    };

    {   // warm-up
        const int e = g * 128 + wv * 16 + l15;
        const int iaR = row[e], iaC = col[e];
        issue_gathers(g, iaR, iaC);
        cr = iaR;
    }
    int ibR = 0, ibC = 0;
    {
        const int gn = g + gstep;
        if (gn < groups) { const int e = gn * 128 + wv * 16 + l15; ibR = row[e]; ibC = col[e]; }
    }

    while (true) {
        const float dx = xr0 - xc0, dy = xr1 - xc1, dz = xr2 - xc2;
        const float sq = dx * dx + dy * dy + dz * dz;

        bf16x8 bfea;
        {
            bf16x8 tv;
            #pragma unroll
            for (int j = 0; j < 4; ++j) { tv[j] = f2bf(cf0[j]); tv[4 + j] = f2bf(cf1[j]); }
            bfea = (l4 < 2) ? tv : zv8;
        }

        // ---- layer1: acc1 = W1c^T@fea + Wa^T@h_r + Wb^T@h_c (chained MFMA,
        //      A-frags streamed from LDS; w1c compact -> zero for l4>=2)
        f32x4 acc1[4];
        #pragma unroll
        for (int t = 0; t < 4; ++t) {
            const bf16x8 wcf = (l4 < 2)
                ? *(const bf16x8*)&wlds[WOFF_W1C + t * 256 + (lane & 31) * 8]
                : zv8;
            const bf16x8 wa0 = *(const bf16x8*)&wlds[WOFF_WA + (size_t)(t * 2 + 0) * 512 + lane * 8];
            const bf16x8 wa1 = *(const bf16x8*)&wlds[WOFF_WA + (size_t)(t * 2 + 1) * 512 + lane * 8];
            const bf16x8 wb0 = *(const bf16x8*)&wlds[WOFF_WB + (size_t)(t * 2 + 0) * 512 + lane * 8];
            const bf16x8 wb1 = *(const bf16x8*)&wlds[WOFF_WB + (size_t)(t * 2 + 1) * 512 + lane * 8];
            acc1[t] = __builtin_amdgcn_mfma_f32_16x16x32_bf16(wcf, bfea, zf, 0, 0, 0);
            acc1[t] = __builtin_amdgcn_mfma_f32_16x16x32_bf16(wa0, bhr0, acc1[t], 0, 0, 0);
            acc1[t] = __builtin_amdgcn_mfma_f32_16x16x32_bf16(wa1, bhr1, acc1[t], 0, 0, 0);
            acc1[t] = __builtin_amdgcn_mfma_f32_16x16x32_bf16(wb0, bhc0, acc1[t], 0, 0, 0);
            acc1[t] = __builtin_amdgcn_mfma_f32_16x16x32_bf16(wb1, bhc1, acc1[t], 0, 0, 0);
        }
        #pragma unroll
        for (int t = 0; t < 4; ++t) {
            const f32x4 b1v = cst_s[0][t * 4 + l4];
            const f32x4 w0v = cst_s[1][t * 4 + l4];
            bf16x4 uu;
            #pragma unroll
            for (int r = 0; r < 4; ++r) {
                const float pre = acc1[t][r] + sq * w0v[r] + b1v[r];
                uu[r] = f2bf(silu_f(pre));
            }
            *(bf16x4*)&us[us_idx(l15, t * 16 + l4 * 4)] = uu;
        }
        LDS_FENCE();

        // ---- prefetch next group's gathers (frag regs consumed above)
        const int gn = g + gstep;
        const bool hn = (gn < groups);
        int nrow = cr;
        if (hn) { issue_gathers(gn, ibR, ibC); nrow = ibR; }

        // ---- layer2: msg' = silu(W2^T @ u1' + b2)  (w2 frags from LDS)
        f32x4 acc2[4];
        {
            const bf16x8 a0 = *(const bf16x8*)&us[us_idx(l15, l4 * 8)];
            const bf16x8 a1 = *(const bf16x8*)&us[us_idx(l15, 32 + l4 * 8)];
            #pragma unroll
            for (int t = 0; t < 4; ++t) {
                const bf16x8 w0 = *(const bf16x8*)&wlds[WOFF_W2 + (size_t)(t * 2 + 0) * 512 + lane * 8];
                const bf16x8 w1 = *(const bf16x8*)&wlds[WOFF_W2 + (size_t)(t * 2 + 1) * 512 + lane * 8];
                acc2[t] = __builtin_amdgcn_mfma_f32_16x16x32_bf16(w0, a0, zf, 0, 0, 0);
                acc2[t] = __builtin_amdgcn_mfma_f32_16x16x32_bf16(w1, a1, acc2[t], 0, 0, 0);
            }
        }
        LDS_FENCE();
        #pragma unroll
        for (int t = 0; t < 4; ++t) {
            const f32x4 b2v = cst_s[2][t * 4 + l4];
            bf16x4 mm;
            #pragma unroll
            for (int r = 0; r < 4; ++r)
                mm[r] = f2bf(silu_f(acc2[t][r] + b2v[r]));
            *(bf16x4*)&us[us_idx(l15, t * 16 + l4 * 4)] = mm;
        }
        LDS_FENCE();

        // ---- layer3 MFMAs (wc1 frags from LDS; issued before atomics)
        f32x4 acc3[4];
        {
            const bf16x8 a0 = *(const bf16x8*)&us[us_idx(l15, l4 * 8)];
            const bf16x8 a1 = *(const bf16x8*)&us[us_idx(l15, 32 + l4 * 8)];
            #pragma unroll
            for (int t = 0; t < 4; ++t) {
                const bf16x8 w0 = *(const bf16x8*)&wlds[WOFF_WC1 + (size_t)(t * 2 + 0) * 512 + lane * 8];
                const bf16x8 w1 = *(const bf16x8*)&wlds[WOFF_WC1 + (size_t)(t * 2 + 1) * 512 + lane * 8];
                acc3[t] = __builtin_amdgcn_mfma_f32_16x16x32_bf16(w0, a0, zf, 0, 0, 0);
                acc3[t] = __builtin_amdgcn_mfma_f32_16x16x32_bf16(w1, a1, acc3[t], 0, 0, 0);
            }
        }

        // ---- tot_msg atomics, packed bf16x2, coalesced (1 line/row/instr)
        #pragma unroll
        for (int r = 0; r < 4; ++r) {
            const int er   = l4 * 4 + r;
            const int rowr = __shfl(cr, er);
            unsigned short* const mb = tot_msg + (size_t)rowr * 64;
            #pragma unroll
            for (int t = 0; t < 2; ++t) {
                const unsigned int pk = *(const unsigned int*)&us[us_idx(er, t * 32 + l15 * 2)];
                atomic_pk_add_bf16(mb + t * 32 + l15 * 2, pk);
            }
        }

        // ---- coord head
        float p = 0.f;
        #pragma unroll
        for (int t = 0; t < 4; ++t) {
            const f32x4 bcv = cst_s[3][t * 4 + l4];
            const f32x4 wcv = cst_s[4][t * 4 + l4];
            #pragma unroll
            for (int r = 0; r < 4; ++r)
                p += silu_f(acc3[t][r] + bcv[r]) * wcv[r];
        }
        p += __shfl_xor(p, 16);
        p += __shfl_xor(p, 32);
        const float coord = p + bc2v;

        const float comp = (l4 == 0) ? dx : (l4 == 1) ? dy : (l4 == 2) ? dz : 0.f;
        const float val  = (l4 == 3) ? 1.0f : comp * coord;
        atomicAdd(&totf4[(size_t)cr * 4 + l4], val);

        if (!hn) break;
        cr = nrow; g = gn;
        {
            const int g2 = gn + gstep;
            if (g2 < groups) { const int e = g2 * 128 + wv * 16 + l15; ibR = row[e]; ibC = col[e]; }
        }
    }
}

// ---------------------------------------------------------------- K3: nodes
__global__ __launch_bounds__(256, 2) void node_kernel(
    const float* __restrict__ x, const unsigned short* __restrict__ h_bf,
    const unsigned short* __restrict__ wfrag,
    const float* __restrict__ bn1, const float* __restrict__ bn2,
    const unsigned short* __restrict__ tot_msg, const float* __restrict__ totf4,
    float* __restrict__ out)
{
    __shared__ __align__(16) short g_s[4][16 * 72];

    const int tid  = threadIdx.x;
    const int lane = tid & 63;
    const int wv   = __builtin_amdgcn_readfirstlane(tid >> 6);
    const int l15  = lane & 15;
    const int l4   = lane >> 4;

    bf16x8 awn1[4][4], awn2[4][2];
    f32x4 bn1r4[4], bn2r4[4];
    #pragma unroll
    for (int t = 0; t < 4; ++t) {
        #pragma unroll
        for (int s = 0; s < 4; ++s)
            awn1[t][s] = *(const bf16x8*)(wfrag + WOFF_WN1 + (size_t)(t * 4 + s) * 512 + lane * 8);
        #pragma unroll
        for (int s = 0; s < 2; ++s)
            awn2[t][s] = *(const bf16x8*)(wfrag + WOFF_WN2 + (size_t)(t * 2 + s) * 512 + lane * 8);
        bn1r4[t] = *(const f32x4*)&bn1[t * 16 + l4 * 4];
        bn2r4[t] = *(const f32x4*)&bn2[t * 16 + l4 * 4];
    }

    const f32x4 zf = {0.f, 0.f, 0.f, 0.f};
    const int n_groups = (N_NODES + 63) / 64;
    float* const out_h = out + (size_t)N_NODES * 3;

    for (int g = blockIdx.x; g < n_groups; g += gridDim.x) {
        const int n16  = g * 64 + wv * 16 + l15;
        const int nc   = (n16 < N_NODES) ? n16 : 0;
        const bool valid = (n16 < N_NODES);

        bf16x8 b[4];
        b[0] = *(const bf16x8*)(h_bf + (size_t)nc * 64 + l4 * 8);
        b[1] = *(const bf16x8*)(h_bf + (size_t)nc * 64 + 32 + l4 * 8);
        b[2] = *(const bf16x8*)(tot_msg + (size_t)nc * 64 + l4 * 8);
        b[3] = *(const bf16x8*)(tot_msg + (size_t)nc * 64 + 32 + l4 * 8);

        #pragma unroll
        for (int t = 0; t < 4; ++t) {
            f32x4 acc = __builtin_amdgcn_mfma_f32_16x16x32_bf16(awn1[t][0], b[0], zf, 0, 0, 0);
            acc = __builtin_amdgcn_mfma_f32_16x16x32_bf16(awn1[t][1], b[1], acc, 0, 0, 0);
            acc = __builtin_amdgcn_mfma_f32_16x16x32_bf16(awn1[t][2], b[2], acc, 0, 0, 0);
            acc = __builtin_amdgcn_mfma_f32_16x16x32_bf16(awn1[t][3], b[3], acc, 0, 0, 0);
            bf16x4 gg;
            #pragma unroll
            for (int r = 0; r < 4; ++r)
                gg[r] = f2bf(silu_f(acc[r] + bn1r4[t][r]));
            *(bf16x4*)&g_s[wv][l15 * 72 + t * 16 + l4 * 4] = gg;
        }
        LDS_FENCE();

        {
            const bf16x8 g0 = *(const bf16x8*)&g_s[wv][l15 * 72 + l4 * 8];
            const bf16x8 g1 = *(const bf16x8*)&g_s[wv][l15 * 72 + 32 + l4 * 8];
            #pragma unroll
            for (int t = 0; t < 4; ++t) {
                f32x4 acc = __builtin_amdgcn_mfma_f32_16x16x32_bf16(awn2[t][0], g0, zf, 0, 0, 0);
                acc = __builtin_amdgcn_mfma_f32_16x16x32_bf16(awn2[t][1], g1, acc, 0, 0, 0);
                if (valid) {
                    f32x4 o;
                    #pragma unroll
                    for (int r = 0; r < 4; ++r) o[r] = acc[r] + bn2r4[t][r];
                    *(f32x4*)&out_h[(size_t)n16 * 64 + t * 16 + l4 * 4] = o;
                }
            }
        }
        LDS_FENCE();

        if (lane < 48) {
            const int nn = lane / 3;
            const int ci = lane % 3;
            const int n  = g * 64 + wv * 16 + nn;
            if (n < N_NODES) {
                const float tot = totf4[n * 4 + ci];
                const float deg = totf4[n * 4 + 3];
                float v = tot / fmaxf(deg, 1.0f);
                v = fminf(fmaxf(v, -100.0f), 100.0f);
                out[n * 3 + ci] = x[n * 3 + ci] + v;
            }
        }
    }
}

// ---------------------------------------------------------------- launcher
extern "C" void kernel_launch(void* const* d_in, const int* in_sizes, int n_in,
                              void* d_out, int out_size, void* d_ws, size_t ws_size,
                              hipStream_t stream) {
    const float* x        = (const float*)d_in[0];
    const float* h        = (const float*)d_in[1];
    const float* edge_fea = (const float*)d_in[2];
    const float* w1e      = (const float*)d_in[3];
    const float* b1e      = (const float*)d_in[4];
    const float* w2e      = (const float*)d_in[5];
    const float* b2e      = (const float*)d_in[6];
    const float* wc1      = (const float*)d_in[7];
    const float* bc1      = (const float*)d_in[8];
    const float* wc2      = (const float*)d_in[9];
    const float* bc2      = (const float*)d_in[10];
    const float* wn1      = (const float*)d_in[11];
    const float* bn1      = (const float*)d_in[12];
    const float* wn2      = (const float*)d_in[13];
    const float* bn2      = (const float*)d_in[14];
    const int*   row      = (const int*)d_in[15];
    const int*   col      = (const int*)d_in[16];
    float* out = (float*)d_out;

    // ws layout: totf4 f32[N*4] | tot_msg bf16[N*64] | h_bf bf16[N*64]
    //            | wfrag bf16[WTOT_SHORTS]   (~13.7 MB total)
    float* totf4 = (float*)d_ws;
    unsigned short* tot_msg = (unsigned short*)(totf4 + (size_t)N_NODES * 4);
    unsigned short* h_bf    = tot_msg + (size_t)N_NODES * 64;
    unsigned short* wfrag   = h_bf + (size_t)N_NODES * 64;

    prep_kernel<<<1024, 256, 0, stream>>>(w1e, w2e, wc1, wn1, wn2, h,
                                          wfrag, h_bf, tot_msg, totf4);
    edge_kernel<<<768, 512, 0, stream>>>(x, edge_fea, w1e, b1e, b2e, bc1, wc2, bc2,
                                         row, col, h_bf, wfrag, tot_msg, totf4);
    node_kernel<<<782, 256, 0, stream>>>(x, h_bf, wfrag, bn1, bn2, tot_msg, totf4, out);
}

// Round 4
// 265.232 us; speedup vs baseline: 1.2811x; 1.2811x over previous
//
#include <hip/hip_runtime.h>
#include <cstddef>

// EGNN layer. Round 13: R12 minus the register cap.
//  - KEEP: LDS diet (u_s XOR-swizzle 16KB, w1c compact 2KB) -> 52.5KB, 3 blocks/CU
//  - REVERT: __launch_bounds__(512,6) -> (512,4). R12's (512,6) forced VGPR 40
//    with inner-loop spills: FETCH 94->289MB, WRITE 125->274MB, VALUBusy 62->41.
//    (512,4) allocates ~56 VGPR (<=64 keeps the 8-wave/SIMD register tier), so
//    LDS remains the only residency limiter -> 3 blocks/CU without spills.
//
// MFMA fragment layouts (gfx950, 16x16x32 bf16, verified learn_hip m89/m91):
//   A: lane holds A[m=lane&15][k=(lane>>4)*8 + j], j=0..7
//   B: lane holds B[k=(lane>>4)*8 + j][n=lane&15]
//   C/D: lane reg r holds D[row=(lane>>4)*4+r][col=lane&15]

#define N_NODES 50000
#define M_EDGES 800000

typedef __attribute__((ext_vector_type(8))) short bf16x8;
typedef __attribute__((ext_vector_type(4))) short bf16x4;
typedef __attribute__((ext_vector_type(2))) short bf16x2;
typedef __attribute__((ext_vector_type(4))) float f32x4;

// ---- global wfrag layout (short offsets). Edge section (first WEDGE_SHORTS)
// is copied verbatim into edge-kernel LDS, so LDS offsets == these offsets.
#define WOFF_WA    0        // w1e rows 1..64   [t*2+s], 8 frags x 512
#define WOFF_WB    4096     // w1e rows 65..128 [t*2+s], 8 frags x 512
#define WOFF_W1C   8192     // w1e rows 129..144 COMPACT: 4 frags x 256 (lanes 0..31)
#define WOFF_W2    9216     // w2e [t*2+s], 8 frags x 512
#define WOFF_WC1   13312    // wc1 [t*2+s], 8 frags x 512
#define WEDGE_SHORTS 17408  // 34816 B staged into edge LDS
#define WOFF_WN1   17408    // wn1 (K=128) [t*4+s], 16 frags x 512
#define WOFF_WN2   25600    // wn2 [t*2+s], 8 frags x 512
#define WTOT_SHORTS 29696

__device__ __forceinline__ float silu_f(float v) {
    return v / (1.0f + __expf(-v));
}

__device__ __forceinline__ short f2bf(float f) {   // RNE float->bf16
    union { float f; unsigned u; } v; v.f = f;
    unsigned r = v.u + 0x7fffu + ((v.u >> 16) & 1u);
    return (short)(r >> 16);
}

__device__ __forceinline__ void atomic_pk_add_bf16(unsigned short* p, unsigned int packed) {
#if __has_builtin(__builtin_amdgcn_global_atomic_fadd_v2bf16)
    typedef bf16x2 __attribute__((address_space(1))) gbf16x2;
    union { unsigned int u; bf16x2 v; } c; c.u = packed;
    __builtin_amdgcn_global_atomic_fadd_v2bf16((gbf16x2*)(unsigned long long)p, c.v);
#else
    asm volatile("global_atomic_pk_add_bf16 %0, %1, off"
                 :: "v"((unsigned long long)p), "v"(packed) : "memory");
#endif
}

#define LDS_FENCE() __asm__ volatile("" ::: "memory")

// u_s swizzle: logical (edge e, short s in [0,64)) -> physical short index.
// XOR of short-index bits 3..5 with e&7 spreads the 128B rows across banks;
// keeps 16B alignment for the bf16x8 reads (s multiple of 8) and 8B for
// the bf16x4 writes (s multiple of 4). Bit 0/1 untouched -> the packed
// uint reads (s multiple of 2) stay contiguous.
__device__ __forceinline__ int us_idx(int e, int s) {
    return e * 64 + (s ^ ((e & 7) << 3));
}

// ---------------------------------------------------------------- K0: prep
// wfrag conversion + h->bf16 + zero tot_msg/totf4, grid-strided.
#define PREP_W   (60 * 64)                  // 3840 (60 64-lane units)
#define PREP_H   (N_NODES * 8)              // 400000  (bf16x8 items of h)
#define PREP_ZM  (N_NODES * 8)              // 400000  (uint4 items of tot_msg)
#define PREP_ZF  (N_NODES)                  // 50000   (f32x4 items of totf4)
#define PREP_TOTAL (PREP_W + PREP_H + PREP_ZM + PREP_ZF)

__global__ __launch_bounds__(256) void prep_kernel(
    const float* __restrict__ w1e, const float* __restrict__ w2e,
    const float* __restrict__ wc1, const float* __restrict__ wn1,
    const float* __restrict__ wn2, const float* __restrict__ h,
    unsigned short* __restrict__ wfrag, unsigned short* __restrict__ h_bf,
    unsigned short* __restrict__ tot_msg, float* __restrict__ totf4)
{
    for (int gid = blockIdx.x * 256 + threadIdx.x; gid < PREP_TOTAL;
         gid += gridDim.x * 256) {
        if (gid < PREP_W) {
            const int unit = gid >> 6, lane = gid & 63;
            const int l15 = lane & 15, l4 = lane >> 4;
            if (unit >= 16 && unit < 20) {
                // w1c compact: 16 real K-rows, lanes 0..31 (k = l4*8+j, l4<2)
                if (lane < 32) {
                    const int t = unit - 16;
                    const int col = t * 16 + l15;
                    bf16x8 v;
                    #pragma unroll
                    for (int j = 0; j < 8; ++j)
                        v[j] = f2bf(w1e[(size_t)(129 + l4 * 8 + j) * 64 + col]);
                    *(bf16x8*)(wfrag + WOFF_W1C + t * 256 + lane * 8) = v;
                }
            } else {
                const float* src; int k0, t, dst;
                if (unit < 8)       { src = w1e; k0 = 1 + (unit & 1) * 32; t = unit >> 1; dst = WOFF_WA + unit * 512; }
                else if (unit < 16) { const int f = unit - 8;  src = w1e; k0 = 65 + (f & 1) * 32; t = f >> 1; dst = WOFF_WB  + f * 512; }
                else if (unit < 28) { const int f = unit - 20; src = w2e; k0 = (f & 1) * 32;      t = f >> 1; dst = WOFF_W2  + f * 512; }
                else if (unit < 36) { const int f = unit - 28; src = wc1; k0 = (f & 1) * 32;      t = f >> 1; dst = WOFF_WC1 + f * 512; }
                else if (unit < 52) { const int f = unit - 36; src = wn1; k0 = (f & 3) * 32;      t = f >> 2; dst = WOFF_WN1 + f * 512; }
                else                { const int f = unit - 52; src = wn2; k0 = (f & 1) * 32;      t = f >> 1; dst = WOFF_WN2 + f * 512; }
                const int col = t * 16 + l15;
                bf16x8 v;
                #pragma unroll
                for (int j = 0; j < 8; ++j)
                    v[j] = f2bf(src[(size_t)(k0 + l4 * 8 + j) * 64 + col]);
                *(bf16x8*)(wfrag + dst + lane * 8) = v;
            }
        } else if (gid < PREP_W + PREP_H) {
            const int j = gid - PREP_W;
            const float* src = h + (size_t)j * 8;
            const f32x4 f0 = *(const f32x4*)src;
            const f32x4 f1 = *(const f32x4*)(src + 4);
            bf16x8 v;
            #pragma unroll
            for (int k = 0; k < 4; ++k) { v[k] = f2bf(f0[k]); v[4 + k] = f2bf(f1[k]); }
            *(bf16x8*)(h_bf + (size_t)j * 8) = v;
        } else if (gid < PREP_W + PREP_H + PREP_ZM) {
            const int j = gid - PREP_W - PREP_H;
            ((uint4*)tot_msg)[j] = make_uint4(0u, 0u, 0u, 0u);
        } else {
            const int j = gid - PREP_W - PREP_H - PREP_ZM;
            const f32x4 zf = {0.f, 0.f, 0.f, 0.f};
            ((f32x4*)totf4)[j] = zf;
        }
    }
}

// ---------------------------------------------------------------- K2: edges
// 512 threads = 8 waves; each wave handles 16 edges per group-iter
// (128 edges per block per iter). All weight frags in LDS (34.8KB).
// LDS total 52.5KB -> 3 blocks/CU (24 waves/CU) as long as VGPR<=64.
__global__ __launch_bounds__(512, 4) void edge_kernel(
    const float* __restrict__ x, const float* __restrict__ edge_fea,
    const float* __restrict__ w1e, const float* __restrict__ b1e,
    const float* __restrict__ b2e, const float* __restrict__ bc1,
    const float* __restrict__ wc2, const float* __restrict__ bc2,
    const int* __restrict__ row, const int* __restrict__ col,
    const unsigned short* __restrict__ h_bf,
    const unsigned short* __restrict__ wfrag,
    unsigned short* __restrict__ tot_msg, float* __restrict__ totf4)
{
    __shared__ __align__(16) short wlds[WEDGE_SHORTS];  // 34816 B
    __shared__ __align__(16) short u_s[8][1024];        // 16384 B (swizzled)
    __shared__ f32x4 cst_s[5][16];                      // 1280 B

    const int tid  = threadIdx.x;
    const int lane = tid & 63;
    const int wv   = __builtin_amdgcn_readfirstlane(tid >> 6);
    const int l15  = lane & 15;
    const int l4   = lane >> 4;

    {   // stage ALL edge-side weight frags into LDS: 34816 B = 2176 uint4
        const uint4* src = (const uint4*)wfrag;
        uint4* dst = (uint4*)wlds;
        for (int i = tid; i < 2176; i += 512) dst[i] = src[i];
    }
    if (tid < 16)       cst_s[0][tid]      = *(const f32x4*)(b1e + tid * 4);
    else if (tid < 32)  cst_s[1][tid - 16] = *(const f32x4*)(w1e + (tid - 16) * 4);
    else if (tid < 48)  cst_s[2][tid - 32] = *(const f32x4*)(b2e + (tid - 32) * 4);
    else if (tid < 64)  cst_s[3][tid - 48] = *(const f32x4*)(bc1 + (tid - 48) * 4);
    else if (tid < 80)  cst_s[4][tid - 64] = *(const f32x4*)(wc2 + (tid - 64) * 4);

    const float bc2v = bc2[0];
    __syncthreads();

    short* const us = &u_s[wv][0];
    const f32x4 zf = {0.f, 0.f, 0.f, 0.f};
    const bf16x8 zv8 = {0, 0, 0, 0, 0, 0, 0, 0};

    // ---- pipelined group loop (128 edges per group)
    const int groups = M_EDGES / 128;    // 6250
    const int gstep  = gridDim.x;        // 768 (persistent blocks, 3/CU)
    int g = blockIdx.x;

    int   cr;
    float xr0, xr1, xr2, xc0, xc1, xc2;
    bf16x8 bhr0, bhr1, bhc0, bhc1;       // h[row], h[col] B-frags (K=64)
    f32x4 cf0 = zf, cf1 = zf;            // fea halves (l4<2 only)

    auto issue_gathers = [&](int gg, int rI, int cI) {
        const float* xr = x + (size_t)rI * 3;
        const float* xc = x + (size_t)cI * 3;
        xr0 = xr[0]; xr1 = xr[1]; xr2 = xr[2];
        xc0 = xc[0]; xc1 = xc[1]; xc2 = xc[2];
        const unsigned short* hr = h_bf + (size_t)rI * 64;
        const unsigned short* hc = h_bf + (size_t)cI * 64;
        bhr0 = *(const bf16x8*)(hr + l4 * 8);
        bhr1 = *(const bf16x8*)(hr + 32 + l4 * 8);
        bhc0 = *(const bf16x8*)(hc + l4 * 8);
        bhc1 = *(const bf16x8*)(hc + 32 + l4 * 8);
        if (l4 < 2) {
            const float* fp = edge_fea + (size_t)(gg * 128 + wv * 16 + l15) * 16 + l4 * 8;
            cf0 = *(const f32x4*)fp;
            cf1 = *(const f32x4*)(fp + 4);
        }
    };

    {   // warm-up
        const int e = g * 128 + wv * 16 + l15;
        const int iaR = row[e], iaC = col[e];
        issue_gathers(g, iaR, iaC);
        cr = iaR;
    }
    int ibR = 0, ibC = 0;
    {
        const int gn = g + gstep;
        if (gn < groups) { const int e = gn * 128 + wv * 16 + l15; ibR = row[e]; ibC = col[e]; }
    }

    while (true) {
        const float dx = xr0 - xc0, dy = xr1 - xc1, dz = xr2 - xc2;
        const float sq = dx * dx + dy * dy + dz * dz;

        bf16x8 bfea;
        {
            bf16x8 tv;
            #pragma unroll
            for (int j = 0; j < 4; ++j) { tv[j] = f2bf(cf0[j]); tv[4 + j] = f2bf(cf1[j]); }
            bfea = (l4 < 2) ? tv : zv8;
        }

        // ---- layer1: acc1 = W1c^T@fea + Wa^T@h_r + Wb^T@h_c (chained MFMA,
        //      A-frags streamed from LDS; w1c compact -> zero for l4>=2)
        f32x4 acc1[4];
        #pragma unroll
        for (int t = 0; t < 4; ++t) {
            const bf16x8 wcf = (l4 < 2)
                ? *(const bf16x8*)&wlds[WOFF_W1C + t * 256 + (lane & 31) * 8]
                : zv8;
            const bf16x8 wa0 = *(const bf16x8*)&wlds[WOFF_WA + (size_t)(t * 2 + 0) * 512 + lane * 8];
            const bf16x8 wa1 = *(const bf16x8*)&wlds[WOFF_WA + (size_t)(t * 2 + 1) * 512 + lane * 8];
            const bf16x8 wb0 = *(const bf16x8*)&wlds[WOFF_WB + (size_t)(t * 2 + 0) * 512 + lane * 8];
            const bf16x8 wb1 = *(const bf16x8*)&wlds[WOFF_WB + (size_t)(t * 2 + 1) * 512 + lane * 8];
            acc1[t] = __builtin_amdgcn_mfma_f32_16x16x32_bf16(wcf, bfea, zf, 0, 0, 0);
            acc1[t] = __builtin_amdgcn_mfma_f32_16x16x32_bf16(wa0, bhr0, acc1[t], 0, 0, 0);
            acc1[t] = __builtin_amdgcn_mfma_f32_16x16x32_bf16(wa1, bhr1, acc1[t], 0, 0, 0);
            acc1[t] = __builtin_amdgcn_mfma_f32_16x16x32_bf16(wb0, bhc0, acc1[t], 0, 0, 0);
            acc1[t] = __builtin_amdgcn_mfma_f32_16x16x32_bf16(wb1, bhc1, acc1[t], 0, 0, 0);
        }
        #pragma unroll
        for (int t = 0; t < 4; ++t) {
            const f32x4 b1v = cst_s[0][t * 4 + l4];
            const f32x4 w0v = cst_s[1][t * 4 + l4];
            bf16x4 uu;
            #pragma unroll
            for (int r = 0; r < 4; ++r) {
                const float pre = acc1[t][r] + sq * w0v[r] + b1v[r];
                uu[r] = f2bf(silu_f(pre));
            }
            *(bf16x4*)&us[us_idx(l15, t * 16 + l4 * 4)] = uu;
        }
        LDS_FENCE();

        // ---- prefetch next group's gathers (frag regs consumed above)
        const int gn = g + gstep;
        const bool hn = (gn < groups);
        int nrow = cr;
        if (hn) { issue_gathers(gn, ibR, ibC); nrow = ibR; }

        // ---- layer2: msg' = silu(W2^T @ u1' + b2)  (w2 frags from LDS)
        f32x4 acc2[4];
        {
            const bf16x8 a0 = *(const bf16x8*)&us[us_idx(l15, l4 * 8)];
            const bf16x8 a1 = *(const bf16x8*)&us[us_idx(l15, 32 + l4 * 8)];
            #pragma unroll
            for (int t = 0; t < 4; ++t) {
                const bf16x8 w0 = *(const bf16x8*)&wlds[WOFF_W2 + (size_t)(t * 2 + 0) * 512 + lane * 8];
                const bf16x8 w1 = *(const bf16x8*)&wlds[WOFF_W2 + (size_t)(t * 2 + 1) * 512 + lane * 8];
                acc2[t] = __builtin_amdgcn_mfma_f32_16x16x32_bf16(w0, a0, zf, 0, 0, 0);
                acc2[t] = __builtin_amdgcn_mfma_f32_16x16x32_bf16(w1, a1, acc2[t], 0, 0, 0);
            }
        }
        LDS_FENCE();
        #pragma unroll
        for (int t = 0; t < 4; ++t) {
            const f32x4 b2v = cst_s[2][t * 4 + l4];
            bf16x4 mm;
            #pragma unroll
            for (int r = 0; r < 4; ++r)
                mm[r] = f2bf(silu_f(acc2[t][r] + b2v[r]));
            *(bf16x4*)&us[us_idx(l15, t * 16 + l4 * 4)] = mm;
        }
        LDS_FENCE();

        // ---- layer3 MFMAs (wc1 frags from LDS; issued before atomics)
        f32x4 acc3[4];
        {
            const bf16x8 a0 = *(const bf16x8*)&us[us_idx(l15, l4 * 8)];
            const bf16x8 a1 = *(const bf16x8*)&us[us_idx(l15, 32 + l4 * 8)];
            #pragma unroll
            for (int t = 0; t < 4; ++t) {
                const bf16x8 w0 = *(const bf16x8*)&wlds[WOFF_WC1 + (size_t)(t * 2 + 0) * 512 + lane * 8];
                const bf16x8 w1 = *(const bf16x8*)&wlds[WOFF_WC1 + (size_t)(t * 2 + 1) * 512 + lane * 8];
                acc3[t] = __builtin_amdgcn_mfma_f32_16x16x32_bf16(w0, a0, zf, 0, 0, 0);
                acc3[t] = __builtin_amdgcn_mfma_f32_16x16x32_bf16(w1, a1, acc3[t], 0, 0, 0);
            }
        }

        // ---- tot_msg atomics, packed bf16x2, coalesced (1 line/row/instr)
        #pragma unroll
        for (int r = 0; r < 4; ++r) {
            const int er   = l4 * 4 + r;
            const int rowr = __shfl(cr, er);
            unsigned short* const mb = tot_msg + (size_t)rowr * 64;
            #pragma unroll
            for (int t = 0; t < 2; ++t) {
                const unsigned int pk = *(const unsigned int*)&us[us_idx(er, t * 32 + l15 * 2)];
                atomic_pk_add_bf16(mb + t * 32 + l15 * 2, pk);
            }
        }

        // ---- coord head
        float p = 0.f;
        #pragma unroll
        for (int t = 0; t < 4; ++t) {
            const f32x4 bcv = cst_s[3][t * 4 + l4];
            const f32x4 wcv = cst_s[4][t * 4 + l4];
            #pragma unroll
            for (int r = 0; r < 4; ++r)
                p += silu_f(acc3[t][r] + bcv[r]) * wcv[r];
        }
        p += __shfl_xor(p, 16);
        p += __shfl_xor(p, 32);
        const float coord = p + bc2v;

        const float comp = (l4 == 0) ? dx : (l4 == 1) ? dy : (l4 == 2) ? dz : 0.f;
        const float val  = (l4 == 3) ? 1.0f : comp * coord;
        atomicAdd(&totf4[(size_t)cr * 4 + l4], val);

        if (!hn) break;
        cr = nrow; g = gn;
        {
            const int g2 = gn + gstep;
            if (g2 < groups) { const int e = g2 * 128 + wv * 16 + l15; ibR = row[e]; ibC = col[e]; }
        }
    }
}

// ---------------------------------------------------------------- K3: nodes
__global__ __launch_bounds__(256, 2) void node_kernel(
    const float* __restrict__ x, const unsigned short* __restrict__ h_bf,
    const unsigned short* __restrict__ wfrag,
    const float* __restrict__ bn1, const float* __restrict__ bn2,
    const unsigned short* __restrict__ tot_msg, const float* __restrict__ totf4,
    float* __restrict__ out)
{
    __shared__ __align__(16) short g_s[4][16 * 72];

    const int tid  = threadIdx.x;
    const int lane = tid & 63;
    const int wv   = __builtin_amdgcn_readfirstlane(tid >> 6);
    const int l15  = lane & 15;
    const int l4   = lane >> 4;

    bf16x8 awn1[4][4], awn2[4][2];
    f32x4 bn1r4[4], bn2r4[4];
    #pragma unroll
    for (int t = 0; t < 4; ++t) {
        #pragma unroll
        for (int s = 0; s < 4; ++s)
            awn1[t][s] = *(const bf16x8*)(wfrag + WOFF_WN1 + (size_t)(t * 4 + s) * 512 + lane * 8);
        #pragma unroll
        for (int s = 0; s < 2; ++s)
            awn2[t][s] = *(const bf16x8*)(wfrag + WOFF_WN2 + (size_t)(t * 2 + s) * 512 + lane * 8);
        bn1r4[t] = *(const f32x4*)&bn1[t * 16 + l4 * 4];
        bn2r4[t] = *(const f32x4*)&bn2[t * 16 + l4 * 4];
    }

    const f32x4 zf = {0.f, 0.f, 0.f, 0.f};
    const int n_groups = (N_NODES + 63) / 64;
    float* const out_h = out + (size_t)N_NODES * 3;

    for (int g = blockIdx.x; g < n_groups; g += gridDim.x) {
        const int n16  = g * 64 + wv * 16 + l15;
        const int nc   = (n16 < N_NODES) ? n16 : 0;
        const bool valid = (n16 < N_NODES);

        bf16x8 b[4];
        b[0] = *(const bf16x8*)(h_bf + (size_t)nc * 64 + l4 * 8);
        b[1] = *(const bf16x8*)(h_bf + (size_t)nc * 64 + 32 + l4 * 8);
        b[2] = *(const bf16x8*)(tot_msg + (size_t)nc * 64 + l4 * 8);
        b[3] = *(const bf16x8*)(tot_msg + (size_t)nc * 64 + 32 + l4 * 8);

        #pragma unroll
        for (int t = 0; t < 4; ++t) {
            f32x4 acc = __builtin_amdgcn_mfma_f32_16x16x32_bf16(awn1[t][0], b[0], zf, 0, 0, 0);
            acc = __builtin_amdgcn_mfma_f32_16x16x32_bf16(awn1[t][1], b[1], acc, 0, 0, 0);
            acc = __builtin_amdgcn_mfma_f32_16x16x32_bf16(awn1[t][2], b[2], acc, 0, 0, 0);
            acc = __builtin_amdgcn_mfma_f32_16x16x32_bf16(awn1[t][3], b[3], acc, 0, 0, 0);
            bf16x4 gg;
            #pragma unroll
            for (int r = 0; r < 4; ++r)
                gg[r] = f2bf(silu_f(acc[r] + bn1r4[t][r]));
            *(bf16x4*)&g_s[wv][l15 * 72 + t * 16 + l4 * 4] = gg;
        }
        LDS_FENCE();

        {
            const bf16x8 g0 = *(const bf16x8*)&g_s[wv][l15 * 72 + l4 * 8];
            const bf16x8 g1 = *(const bf16x8*)&g_s[wv][l15 * 72 + 32 + l4 * 8];
            #pragma unroll
            for (int t = 0; t < 4; ++t) {
                f32x4 acc = __builtin_amdgcn_mfma_f32_16x16x32_bf16(awn2[t][0], g0, zf, 0, 0, 0);
                acc = __builtin_amdgcn_mfma_f32_16x16x32_bf16(awn2[t][1], g1, acc, 0, 0, 0);
                if (valid) {
                    f32x4 o;
                    #pragma unroll
                    for (int r = 0; r < 4; ++r) o[r] = acc[r] + bn2r4[t][r];
                    *(f32x4*)&out_h[(size_t)n16 * 64 + t * 16 + l4 * 4] = o;
                }
            }
        }
        LDS_FENCE();

        if (lane < 48) {
            const int nn = lane / 3;
            const int ci = lane % 3;
            const int n  = g * 64 + wv * 16 + nn;
            if (n < N_NODES) {
                const float tot = totf4[n * 4 + ci];
                const float deg = totf4[n * 4 + 3];
                float v = tot / fmaxf(deg, 1.0f);
                v = fminf(fmaxf(v, -100.0f), 100.0f);
                out[n * 3 + ci] = x[n * 3 + ci] + v;
            }
        }
    }
}

// ---------------------------------------------------------------- launcher
extern "C" void kernel_launch(void* const* d_in, const int* in_sizes, int n_in,
                              void* d_out, int out_size, void* d_ws, size_t ws_size,
                              hipStream_t stream) {
    const float* x        = (const float*)d_in[0];
    const float* h        = (const float*)d_in[1];
    const float* edge_fea = (const float*)d_in[2];
    const float* w1e      = (const float*)d_in[3];
    const float* b1e      = (const float*)d_in[4];
    const float* w2e      = (const float*)d_in[5];
    const float* b2e      = (const float*)d_in[6];
    const float* wc1      = (const float*)d_in[7];
    const float* bc1      = (const float*)d_in[8];
    const float* wc2      = (const float*)d_in[9];
    const float* bc2      = (const float*)d_in[10];
    const float* wn1      = (const float*)d_in[11];
    const float* bn1      = (const float*)d_in[12];
    const float* wn2      = (const float*)d_in[13];
    const float* bn2      = (const float*)d_in[14];
    const int*   row      = (const int*)d_in[15];
    const int*   col      = (const int*)d_in[16];
    float* out = (float*)d_out;

    // ws layout: totf4 f32[N*4] | tot_msg bf16[N*64] | h_bf bf16[N*64]
    //            | wfrag bf16[WTOT_SHORTS]   (~13.7 MB total)
    float* totf4 = (float*)d_ws;
    unsigned short* tot_msg = (unsigned short*)(totf4 + (size_t)N_NODES * 4);
    unsigned short* h_bf    = tot_msg + (size_t)N_NODES * 64;
    unsigned short* wfrag   = h_bf + (size_t)N_NODES * 64;

    prep_kernel<<<1024, 256, 0, stream>>>(w1e, w2e, wc1, wn1, wn2, h,
                                          wfrag, h_bf, tot_msg, totf4);
    edge_kernel<<<768, 512, 0, stream>>>(x, edge_fea, w1e, b1e, b2e, bc1, wc2, bc2,
                                         row, col, h_bf, wfrag, tot_msg, totf4);
    node_kernel<<<782, 256, 0, stream>>>(x, h_bf, wfrag, bn1, bn2, tot_msg, totf4, out);
}

// Round 5
// 262.223 us; speedup vs baseline: 1.2958x; 1.0115x over previous
//
#include <hip/hip_runtime.h>
#include <cstddef>

// EGNN layer. Round 14: VALU diet on the hot paths.
//  - silu: f32 division (v_div_* ~10 instr) -> __builtin_amdgcn_rcpf (1 instr).
//    ~450 VALU instrs/wave-iter saved across layer1/layer2/coord epilogues.
//  - bf16 packing: manual RNE f2bf (~4 instr/value) -> v_cvt_pk_bf16_f32
//    inline asm (1 instr / 2 values) in edge epilogues, bfea, prep h-convert,
//    node epilogue. ~140 instrs/iter saved.
//  - structure unchanged from R13: 512-thr blocks, all edge weights in LDS
//    (52.5KB), persistent grid 768, __launch_bounds__(512,4) (no reg cap —
//    R12 showed (512,6) spills catastrophically).
//
// MFMA fragment layouts (gfx950, 16x16x32 bf16, verified learn_hip m89/m91):
//   A: lane holds A[m=lane&15][k=(lane>>4)*8 + j], j=0..7
//   B: lane holds B[k=(lane>>4)*8 + j][n=lane&15]
//   C/D: lane reg r holds D[row=(lane>>4)*4+r][col=lane&15]

#define N_NODES 50000
#define M_EDGES 800000

typedef __attribute__((ext_vector_type(8))) short bf16x8;
typedef __attribute__((ext_vector_type(4))) short bf16x4;
typedef __attribute__((ext_vector_type(2))) short bf16x2;
typedef __attribute__((ext_vector_type(4))) float f32x4;

// ---- global wfrag layout (short offsets). Edge section (first WEDGE_SHORTS)
// is copied verbatim into edge-kernel LDS, so LDS offsets == these offsets.
#define WOFF_WA    0        // w1e rows 1..64   [t*2+s], 8 frags x 512
#define WOFF_WB    4096     // w1e rows 65..128 [t*2+s], 8 frags x 512
#define WOFF_W1C   8192     // w1e rows 129..144 COMPACT: 4 frags x 256 (lanes 0..31)
#define WOFF_W2    9216     // w2e [t*2+s], 8 frags x 512
#define WOFF_WC1   13312    // wc1 [t*2+s], 8 frags x 512
#define WEDGE_SHORTS 17408  // 34816 B staged into edge LDS
#define WOFF_WN1   17408    // wn1 (K=128) [t*4+s], 16 frags x 512
#define WOFF_WN2   25600    // wn2 [t*2+s], 8 frags x 512
#define WTOT_SHORTS 29696

// fast silu: v * rcp(1+exp(-v)). v_rcp_f32 is ~1 ulp approx — well inside
// the bf16 rounding noise this pipeline already has.
__device__ __forceinline__ float silu_f(float v) {
    return v * __builtin_amdgcn_rcpf(1.0f + __expf(-v));
}

__device__ __forceinline__ short f2bf(float f) {   // RNE float->bf16 (cold paths)
    union { float f; unsigned u; } v; v.f = f;
    unsigned r = v.u + 0x7fffu + ((v.u >> 16) & 1u);
    return (short)(r >> 16);
}

// hardware packed f32x2 -> bf16x2 (RNE), gfx950. No builtin (m240) -> asm.
__device__ __forceinline__ unsigned cvt_pk_bf16(float lo, float hi) {
    unsigned r;
    asm("v_cvt_pk_bf16_f32 %0, %1, %2" : "=v"(r) : "v"(lo), "v"(hi));
    return r;
}

__device__ __forceinline__ void atomic_pk_add_bf16(unsigned short* p, unsigned int packed) {
#if __has_builtin(__builtin_amdgcn_global_atomic_fadd_v2bf16)
    typedef bf16x2 __attribute__((address_space(1))) gbf16x2;
    union { unsigned int u; bf16x2 v; } c; c.u = packed;
    __builtin_amdgcn_global_atomic_fadd_v2bf16((gbf16x2*)(unsigned long long)p, c.v);
#else
    asm volatile("global_atomic_pk_add_bf16 %0, %1, off"
                 :: "v"((unsigned long long)p), "v"(packed) : "memory");
#endif
}

#define LDS_FENCE() __asm__ volatile("" ::: "memory")

// u_s swizzle: logical (edge e, short s in [0,64)) -> physical short index.
// XOR of short-index bits 3..5 with e&7 spreads the 128B rows across banks;
// 16B alignment preserved for bf16x8 reads, 8B for bf16x4/uint2 writes.
__device__ __forceinline__ int us_idx(int e, int s) {
    return e * 64 + (s ^ ((e & 7) << 3));
}

// ---------------------------------------------------------------- K0: prep
// wfrag conversion + h->bf16 + zero tot_msg/totf4, grid-strided.
#define PREP_W   (60 * 64)                  // 3840 (60 64-lane units)
#define PREP_H   (N_NODES * 8)              // 400000  (bf16x8 items of h)
#define PREP_ZM  (N_NODES * 8)              // 400000  (uint4 items of tot_msg)
#define PREP_ZF  (N_NODES)                  // 50000   (f32x4 items of totf4)
#define PREP_TOTAL (PREP_W + PREP_H + PREP_ZM + PREP_ZF)

__global__ __launch_bounds__(256) void prep_kernel(
    const float* __restrict__ w1e, const float* __restrict__ w2e,
    const float* __restrict__ wc1, const float* __restrict__ wn1,
    const float* __restrict__ wn2, const float* __restrict__ h,
    unsigned short* __restrict__ wfrag, unsigned short* __restrict__ h_bf,
    unsigned short* __restrict__ tot_msg, float* __restrict__ totf4)
{
    for (int gid = blockIdx.x * 256 + threadIdx.x; gid < PREP_TOTAL;
         gid += gridDim.x * 256) {
        if (gid < PREP_W) {
            const int unit = gid >> 6, lane = gid & 63;
            const int l15 = lane & 15, l4 = lane >> 4;
            if (unit >= 16 && unit < 20) {
                // w1c compact: 16 real K-rows, lanes 0..31 (k = l4*8+j, l4<2)
                if (lane < 32) {
                    const int t = unit - 16;
                    const int col = t * 16 + l15;
                    bf16x8 v;
                    #pragma unroll
                    for (int j = 0; j < 8; ++j)
                        v[j] = f2bf(w1e[(size_t)(129 + l4 * 8 + j) * 64 + col]);
                    *(bf16x8*)(wfrag + WOFF_W1C + t * 256 + lane * 8) = v;
                }
            } else {
                const float* src; int k0, t, dst;
                if (unit < 8)       { src = w1e; k0 = 1 + (unit & 1) * 32; t = unit >> 1; dst = WOFF_WA + unit * 512; }
                else if (unit < 16) { const int f = unit - 8;  src = w1e; k0 = 65 + (f & 1) * 32; t = f >> 1; dst = WOFF_WB  + f * 512; }
                else if (unit < 28) { const int f = unit - 20; src = w2e; k0 = (f & 1) * 32;      t = f >> 1; dst = WOFF_W2  + f * 512; }
                else if (unit < 36) { const int f = unit - 28; src = wc1; k0 = (f & 1) * 32;      t = f >> 1; dst = WOFF_WC1 + f * 512; }
                else if (unit < 52) { const int f = unit - 36; src = wn1; k0 = (f & 3) * 32;      t = f >> 2; dst = WOFF_WN1 + f * 512; }
                else                { const int f = unit - 52; src = wn2; k0 = (f & 1) * 32;      t = f >> 1; dst = WOFF_WN2 + f * 512; }
                const int col = t * 16 + l15;
                bf16x8 v;
                #pragma unroll
                for (int j = 0; j < 8; ++j)
                    v[j] = f2bf(src[(size_t)(k0 + l4 * 8 + j) * 64 + col]);
                *(bf16x8*)(wfrag + dst + lane * 8) = v;
            }
        } else if (gid < PREP_W + PREP_H) {
            const int j = gid - PREP_W;
            const float* src = h + (size_t)j * 8;
            const f32x4 f0 = *(const f32x4*)src;
            const f32x4 f1 = *(const f32x4*)(src + 4);
            union { unsigned u[4]; bf16x8 v8; } ub;
            ub.u[0] = cvt_pk_bf16(f0[0], f0[1]);
            ub.u[1] = cvt_pk_bf16(f0[2], f0[3]);
            ub.u[2] = cvt_pk_bf16(f1[0], f1[1]);
            ub.u[3] = cvt_pk_bf16(f1[2], f1[3]);
            *(bf16x8*)(h_bf + (size_t)j * 8) = ub.v8;
        } else if (gid < PREP_W + PREP_H + PREP_ZM) {
            const int j = gid - PREP_W - PREP_H;
            ((uint4*)tot_msg)[j] = make_uint4(0u, 0u, 0u, 0u);
        } else {
            const int j = gid - PREP_W - PREP_H - PREP_ZM;
            const f32x4 zf = {0.f, 0.f, 0.f, 0.f};
            ((f32x4*)totf4)[j] = zf;
        }
    }
}

// ---------------------------------------------------------------- K2: edges
// 512 threads = 8 waves; each wave handles 16 edges per group-iter
// (128 edges per block per iter). All weight frags in LDS (34.8KB).
// LDS total 52.5KB; VGPR ~60 -> no spills at (512,4).
__global__ __launch_bounds__(512, 4) void edge_kernel(
    const float* __restrict__ x, const float* __restrict__ edge_fea,
    const float* __restrict__ w1e, const float* __restrict__ b1e,
    const float* __restrict__ b2e, const float* __restrict__ bc1,
    const float* __restrict__ wc2, const float* __restrict__ bc2,
    const int* __restrict__ row, const int* __restrict__ col,
    const unsigned short* __restrict__ h_bf,
    const unsigned short* __restrict__ wfrag,
    unsigned short* __restrict__ tot_msg, float* __restrict__ totf4)
{
    __shared__ __align__(16) short wlds[WEDGE_SHORTS];  // 34816 B
    __shared__ __align__(16) short u_s[8][1024];        // 16384 B (swizzled)
    __shared__ f32x4 cst_s[5][16];                      // 1280 B

    const int tid  = threadIdx.x;
    const int lane = tid & 63;
    const int wv   = __builtin_amdgcn_readfirstlane(tid >> 6);
    const int l15  = lane & 15;
    const int l4   = lane >> 4;

    {   // stage ALL edge-side weight frags into LDS: 34816 B = 2176 uint4
        const uint4* src = (const uint4*)wfrag;
        uint4* dst = (uint4*)wlds;
        for (int i = tid; i < 2176; i += 512) dst[i] = src[i];
    }
    if (tid < 16)       cst_s[0][tid]      = *(const f32x4*)(b1e + tid * 4);
    else if (tid < 32)  cst_s[1][tid - 16] = *(const f32x4*)(w1e + (tid - 16) * 4);
    else if (tid < 48)  cst_s[2][tid - 32] = *(const f32x4*)(b2e + (tid - 32) * 4);
    else if (tid < 64)  cst_s[3][tid - 48] = *(const f32x4*)(bc1 + (tid - 48) * 4);
    else if (tid < 80)  cst_s[4][tid - 64] = *(const f32x4*)(wc2 + (tid - 64) * 4);

    const float bc2v = bc2[0];
    __syncthreads();

    short* const us = &u_s[wv][0];
    const f32x4 zf = {0.f, 0.f, 0.f, 0.f};
    const bf16x8 zv8 = {0, 0, 0, 0, 0, 0, 0, 0};

    // ---- pipelined group loop (128 edges per group)
    const int groups = M_EDGES / 128;    // 6250
    const int gstep  = gridDim.x;        // 768 (persistent blocks)
    int g = blockIdx.x;

    int   cr;
    float xr0, xr1, xr2, xc0, xc1, xc2;
    bf16x8 bhr0, bhr1, bhc0, bhc1;       // h[row], h[col] B-frags (K=64)
    f32x4 cf0 = zf, cf1 = zf;            // fea halves (l4<2 only)

    auto issue_gathers = [&](int gg, int rI, int cI) {
        const float* xr = x + (size_t)rI * 3;
        const float* xc = x + (size_t)cI * 3;
        xr0 = xr[0]; xr1 = xr[1]; xr2 = xr[2];
        xc0 = xc[0]; xc1 = xc[1]; xc2 = xc[2];
        const unsigned short* hr = h_bf + (size_t)rI * 64;
        const unsigned short* hc = h_bf + (size_t)cI * 64;
        bhr0 = *(const bf16x8*)(hr + l4 * 8);
        bhr1 = *(const bf16x8*)(hr + 32 + l4 * 8);
        bhc0 = *(const bf16x8*)(hc + l4 * 8);
        bhc1 = *(const bf16x8*)(hc + 32 + l4 * 8);
        if (l4 < 2) {
            const float* fp = edge_fea + (size_t)(gg * 128 + wv * 16 + l15) * 16 + l4 * 8;
            cf0 = *(const f32x4*)fp;
            cf1 = *(const f32x4*)(fp + 4);
        }
    };

    {   // warm-up
        const int e = g * 128 + wv * 16 + l15;
        const int iaR = row[e], iaC = col[e];
        issue_gathers(g, iaR, iaC);
        cr = iaR;
    }
    int ibR = 0, ibC = 0;
    {
        const int gn = g + gstep;
        if (gn < groups) { const int e = gn * 128 + wv * 16 + l15; ibR = row[e]; ibC = col[e]; }
    }

    while (true) {
        const float dx = xr0 - xc0, dy = xr1 - xc1, dz = xr2 - xc2;
        const float sq = dx * dx + dy * dy + dz * dz;

        bf16x8 bfea;
        {
            union { unsigned u[4]; bf16x8 v8; } ub;
            ub.u[0] = cvt_pk_bf16(cf0[0], cf0[1]);
            ub.u[1] = cvt_pk_bf16(cf0[2], cf0[3]);
            ub.u[2] = cvt_pk_bf16(cf1[0], cf1[1]);
            ub.u[3] = cvt_pk_bf16(cf1[2], cf1[3]);
            bfea = (l4 < 2) ? ub.v8 : zv8;
        }

        // ---- layer1: acc1 = W1c^T@fea + Wa^T@h_r + Wb^T@h_c (chained MFMA,
        //      A-frags streamed from LDS; w1c compact -> zero for l4>=2)
        f32x4 acc1[4];
        #pragma unroll
        for (int t = 0; t < 4; ++t) {
            const bf16x8 wcf = (l4 < 2)
                ? *(const bf16x8*)&wlds[WOFF_W1C + t * 256 + (lane & 31) * 8]
                : zv8;
            const bf16x8 wa0 = *(const bf16x8*)&wlds[WOFF_WA + (size_t)(t * 2 + 0) * 512 + lane * 8];
            const bf16x8 wa1 = *(const bf16x8*)&wlds[WOFF_WA + (size_t)(t * 2 + 1) * 512 + lane * 8];
            const bf16x8 wb0 = *(const bf16x8*)&wlds[WOFF_WB + (size_t)(t * 2 + 0) * 512 + lane * 8];
            const bf16x8 wb1 = *(const bf16x8*)&wlds[WOFF_WB + (size_t)(t * 2 + 1) * 512 + lane * 8];
            acc1[t] = __builtin_amdgcn_mfma_f32_16x16x32_bf16(wcf, bfea, zf, 0, 0, 0);
            acc1[t] = __builtin_amdgcn_mfma_f32_16x16x32_bf16(wa0, bhr0, acc1[t], 0, 0, 0);
            acc1[t] = __builtin_amdgcn_mfma_f32_16x16x32_bf16(wa1, bhr1, acc1[t], 0, 0, 0);
            acc1[t] = __builtin_amdgcn_mfma_f32_16x16x32_bf16(wb0, bhc0, acc1[t], 0, 0, 0);
            acc1[t] = __builtin_amdgcn_mfma_f32_16x16x32_bf16(wb1, bhc1, acc1[t], 0, 0, 0);
        }
        #pragma unroll
        for (int t = 0; t < 4; ++t) {
            const f32x4 b1v = cst_s[0][t * 4 + l4];
            const f32x4 w0v = cst_s[1][t * 4 + l4];
            float sv[4];
            #pragma unroll
            for (int r = 0; r < 4; ++r)
                sv[r] = silu_f(acc1[t][r] + sq * w0v[r] + b1v[r]);
            uint2 pk;
            pk.x = cvt_pk_bf16(sv[0], sv[1]);
            pk.y = cvt_pk_bf16(sv[2], sv[3]);
            *(uint2*)&us[us_idx(l15, t * 16 + l4 * 4)] = pk;
        }
        LDS_FENCE();

        // ---- prefetch next group's gathers (frag regs consumed above)
        const int gn = g + gstep;
        const bool hn = (gn < groups);
        int nrow = cr;
        if (hn) { issue_gathers(gn, ibR, ibC); nrow = ibR; }

        // ---- layer2: msg' = silu(W2^T @ u1' + b2)  (w2 frags from LDS)
        f32x4 acc2[4];
        {
            const bf16x8 a0 = *(const bf16x8*)&us[us_idx(l15, l4 * 8)];
            const bf16x8 a1 = *(const bf16x8*)&us[us_idx(l15, 32 + l4 * 8)];
            #pragma unroll
            for (int t = 0; t < 4; ++t) {
                const bf16x8 w0 = *(const bf16x8*)&wlds[WOFF_W2 + (size_t)(t * 2 + 0) * 512 + lane * 8];
                const bf16x8 w1 = *(const bf16x8*)&wlds[WOFF_W2 + (size_t)(t * 2 + 1) * 512 + lane * 8];
                acc2[t] = __builtin_amdgcn_mfma_f32_16x16x32_bf16(w0, a0, zf, 0, 0, 0);
                acc2[t] = __builtin_amdgcn_mfma_f32_16x16x32_bf16(w1, a1, acc2[t], 0, 0, 0);
            }
        }
        LDS_FENCE();
        #pragma unroll
        for (int t = 0; t < 4; ++t) {
            const f32x4 b2v = cst_s[2][t * 4 + l4];
            float sv[4];
            #pragma unroll
            for (int r = 0; r < 4; ++r)
                sv[r] = silu_f(acc2[t][r] + b2v[r]);
            uint2 pk;
            pk.x = cvt_pk_bf16(sv[0], sv[1]);
            pk.y = cvt_pk_bf16(sv[2], sv[3]);
            *(uint2*)&us[us_idx(l15, t * 16 + l4 * 4)] = pk;
        }
        LDS_FENCE();

        // ---- layer3 MFMAs (wc1 frags from LDS; issued before atomics)
        f32x4 acc3[4];
        {
            const bf16x8 a0 = *(const bf16x8*)&us[us_idx(l15, l4 * 8)];
            const bf16x8 a1 = *(const bf16x8*)&us[us_idx(l15, 32 + l4 * 8)];
            #pragma unroll
            for (int t = 0; t < 4; ++t) {
                const bf16x8 w0 = *(const bf16x8*)&wlds[WOFF_WC1 + (size_t)(t * 2 + 0) * 512 + lane * 8];
                const bf16x8 w1 = *(const bf16x8*)&wlds[WOFF_WC1 + (size_t)(t * 2 + 1) * 512 + lane * 8];
                acc3[t] = __builtin_amdgcn_mfma_f32_16x16x32_bf16(w0, a0, zf, 0, 0, 0);
                acc3[t] = __builtin_amdgcn_mfma_f32_16x16x32_bf16(w1, a1, acc3[t], 0, 0, 0);
            }
        }

        // ---- tot_msg atomics, packed bf16x2, coalesced (1 line/row/instr)
        #pragma unroll
        for (int r = 0; r < 4; ++r) {
            const int er   = l4 * 4 + r;
            const int rowr = __shfl(cr, er);
            unsigned short* const mb = tot_msg + (size_t)rowr * 64;
            #pragma unroll
            for (int t = 0; t < 2; ++t) {
                const unsigned int pk = *(const unsigned int*)&us[us_idx(er, t * 32 + l15 * 2)];
                atomic_pk_add_bf16(mb + t * 32 + l15 * 2, pk);
            }
        }

        // ---- coord head
        float p = 0.f;
        #pragma unroll
        for (int t = 0; t < 4; ++t) {
            const f32x4 bcv = cst_s[3][t * 4 + l4];
            const f32x4 wcv = cst_s[4][t * 4 + l4];
            #pragma unroll
            for (int r = 0; r < 4; ++r)
                p += silu_f(acc3[t][r] + bcv[r]) * wcv[r];
        }
        p += __shfl_xor(p, 16);
        p += __shfl_xor(p, 32);
        const float coord = p + bc2v;

        const float comp = (l4 == 0) ? dx : (l4 == 1) ? dy : (l4 == 2) ? dz : 0.f;
        const float val  = (l4 == 3) ? 1.0f : comp * coord;
        atomicAdd(&totf4[(size_t)cr * 4 + l4], val);

        if (!hn) break;
        cr = nrow; g = gn;
        {
            const int g2 = gn + gstep;
            if (g2 < groups) { const int e = g2 * 128 + wv * 16 + l15; ibR = row[e]; ibC = col[e]; }
        }
    }
}

// ---------------------------------------------------------------- K3: nodes
__global__ __launch_bounds__(256, 2) void node_kernel(
    const float* __restrict__ x, const unsigned short* __restrict__ h_bf,
    const unsigned short* __restrict__ wfrag,
    const float* __restrict__ bn1, const float* __restrict__ bn2,
    const unsigned short* __restrict__ tot_msg, const float* __restrict__ totf4,
    float* __restrict__ out)
{
    __shared__ __align__(16) short g_s[4][16 * 72];

    const int tid  = threadIdx.x;
    const int lane = tid & 63;
    const int wv   = __builtin_amdgcn_readfirstlane(tid >> 6);
    const int l15  = lane & 15;
    const int l4   = lane >> 4;

    bf16x8 awn1[4][4], awn2[4][2];
    f32x4 bn1r4[4], bn2r4[4];
    #pragma unroll
    for (int t = 0; t < 4; ++t) {
        #pragma unroll
        for (int s = 0; s < 4; ++s)
            awn1[t][s] = *(const bf16x8*)(wfrag + WOFF_WN1 + (size_t)(t * 4 + s) * 512 + lane * 8);
        #pragma unroll
        for (int s = 0; s < 2; ++s)
            awn2[t][s] = *(const bf16x8*)(wfrag + WOFF_WN2 + (size_t)(t * 2 + s) * 512 + lane * 8);
        bn1r4[t] = *(const f32x4*)&bn1[t * 16 + l4 * 4];
        bn2r4[t] = *(const f32x4*)&bn2[t * 16 + l4 * 4];
    }

    const f32x4 zf = {0.f, 0.f, 0.f, 0.f};
    const int n_groups = (N_NODES + 63) / 64;
    float* const out_h = out + (size_t)N_NODES * 3;

    for (int g = blockIdx.x; g < n_groups; g += gridDim.x) {
        const int n16  = g * 64 + wv * 16 + l15;
        const int nc   = (n16 < N_NODES) ? n16 : 0;
        const bool valid = (n16 < N_NODES);

        bf16x8 b[4];
        b[0] = *(const bf16x8*)(h_bf + (size_t)nc * 64 + l4 * 8);
        b[1] = *(const bf16x8*)(h_bf + (size_t)nc * 64 + 32 + l4 * 8);
        b[2] = *(const bf16x8*)(tot_msg + (size_t)nc * 64 + l4 * 8);
        b[3] = *(const bf16x8*)(tot_msg + (size_t)nc * 64 + 32 + l4 * 8);

        #pragma unroll
        for (int t = 0; t < 4; ++t) {
            f32x4 acc = __builtin_amdgcn_mfma_f32_16x16x32_bf16(awn1[t][0], b[0], zf, 0, 0, 0);
            acc = __builtin_amdgcn_mfma_f32_16x16x32_bf16(awn1[t][1], b[1], acc, 0, 0, 0);
            acc = __builtin_amdgcn_mfma_f32_16x16x32_bf16(awn1[t][2], b[2], acc, 0, 0, 0);
            acc = __builtin_amdgcn_mfma_f32_16x16x32_bf16(awn1[t][3], b[3], acc, 0, 0, 0);
            float sv[4];
            #pragma unroll
            for (int r = 0; r < 4; ++r)
                sv[r] = silu_f(acc[r] + bn1r4[t][r]);
            uint2 pk;
            pk.x = cvt_pk_bf16(sv[0], sv[1]);
            pk.y = cvt_pk_bf16(sv[2], sv[3]);
            *(uint2*)&g_s[wv][l15 * 72 + t * 16 + l4 * 4] = pk;
        }
        LDS_FENCE();

        {
            const bf16x8 g0 = *(const bf16x8*)&g_s[wv][l15 * 72 + l4 * 8];
            const bf16x8 g1 = *(const bf16x8*)&g_s[wv][l15 * 72 + 32 + l4 * 8];
            #pragma unroll
            for (int t = 0; t < 4; ++t) {
                f32x4 acc = __builtin_amdgcn_mfma_f32_16x16x32_bf16(awn2[t][0], g0, zf, 0, 0, 0);
                acc = __builtin_amdgcn_mfma_f32_16x16x32_bf16(awn2[t][1], g1, acc, 0, 0, 0);
                if (valid) {
                    f32x4 o;
                    #pragma unroll
                    for (int r = 0; r < 4; ++r) o[r] = acc[r] + bn2r4[t][r];
                    *(f32x4*)&out_h[(size_t)n16 * 64 + t * 16 + l4 * 4] = o;
                }
            }
        }
        LDS_FENCE();

        if (lane < 48) {
            const int nn = lane / 3;
            const int ci = lane % 3;
            const int n  = g * 64 + wv * 16 + nn;
            if (n < N_NODES) {
                const float tot = totf4[n * 4 + ci];
                const float deg = totf4[n * 4 + 3];
                float v = tot / fmaxf(deg, 1.0f);
                v = fminf(fmaxf(v, -100.0f), 100.0f);
                out[n * 3 + ci] = x[n * 3 + ci] + v;
            }
        }
    }
}

// ---------------------------------------------------------------- launcher
extern "C" void kernel_launch(void* const* d_in, const int* in_sizes, int n_in,
                              void* d_out, int out_size, void* d_ws, size_t ws_size,
                              hipStream_t stream) {
    const float* x        = (const float*)d_in[0];
    const float* h        = (const float*)d_in[1];
    const float* edge_fea = (const float*)d_in[2];
    const float* w1e      = (const float*)d_in[3];
    const float* b1e      = (const float*)d_in[4];
    const float* w2e      = (const float*)d_in[5];
    const float* b2e      = (const float*)d_in[6];
    const float* wc1      = (const float*)d_in[7];
    const float* bc1      = (const float*)d_in[8];
    const float* wc2      = (const float*)d_in[9];
    const float* bc2      = (const float*)d_in[10];
    const float* wn1      = (const float*)d_in[11];
    const float* bn1      = (const float*)d_in[12];
    const float* wn2      = (const float*)d_in[13];
    const float* bn2      = (const float*)d_in[14];
    const int*   row      = (const int*)d_in[15];
    const int*   col      = (const int*)d_in[16];
    float* out = (float*)d_out;

    // ws layout: totf4 f32[N*4] | tot_msg bf16[N*64] | h_bf bf16[N*64]
    //            | wfrag bf16[WTOT_SHORTS]   (~13.7 MB total)
    float* totf4 = (float*)d_ws;
    unsigned short* tot_msg = (unsigned short*)(totf4 + (size_t)N_NODES * 4);
    unsigned short* h_bf    = tot_msg + (size_t)N_NODES * 64;
    unsigned short* wfrag   = h_bf + (size_t)N_NODES * 64;

    prep_kernel<<<1024, 256, 0, stream>>>(w1e, w2e, wc1, wn1, wn2, h,
                                          wfrag, h_bf, tot_msg, totf4);
    edge_kernel<<<768, 512, 0, stream>>>(x, edge_fea, w1e, b1e, b2e, bc1, wc2, bc2,
                                         row, col, h_bf, wfrag, tot_msg, totf4);
    node_kernel<<<782, 256, 0, stream>>>(x, h_bf, wfrag, bn1, bn2, tot_msg, totf4, out);
}